// Round 10
// baseline (962.096 us; speedup 1.0000x reference)
//
#include <hip/hip_runtime.h>

#pragma clang fp contract(off)

typedef __attribute__((ext_vector_type(8))) short short8;
typedef __attribute__((ext_vector_type(4))) float f32x4;

#define MARGIN 0.02f

static __device__ __forceinline__ unsigned short f2b(float f) {
    union { float f; unsigned u; } x; x.f = f;
    unsigned u = x.u;
    return (unsigned short)((u + 0x7FFFu + ((u >> 16) & 1u)) >> 16);
}

// Bit-exact np distance: dot = single-accumulator ascending-k FMA chain
// on FULL-PRECISION fp32 z from global; d = (zn - 2*dot) + en.
// ES = element stride of the codebook column (1 for Et, 1024 for E).
template <int ES>
static __device__ __forceinline__ float np_dist(
    const float* __restrict__ zr, const float* __restrict__ ecol,
    float zn, float en) {
    float c = 0.f;
    #pragma unroll
    for (int i = 0; i < 64; ++i) c = fmaf(zr[i], ecol[i * ES], c);
    float t = zn - 2.f * c;
    return t + en;
}

// ---------------------------------------------------------------------------
// Prep kernel (grid 16 x 256) — SEPARATE LAUNCH (kernel-boundary coherence).
// R6/R7/R9-proven content (unchanged):
//  - sT[64][65]: LDS tile of E (coalesced reads, padded)
//  - Et[k*64+d]: fp32 transpose for exact re-eval + gather            [if ET]
//  - Eb: bf16 codebook in EXACT per-lane MFMA B-fragment layout:
//      u16 element (c*1024 + s*512 + l*8 + j) = bf16(E[d][col]),
//      d = s*32 + (l>>4)*8 + j, col = c*16 + (l&15)
//    so lane l's fragment for tile c is 16 B CONTIGUOUS at Eb + c*1024 + l*8.
//  - enorm[k]: ascending-d fmaf chain (np axis-0 reduce order)
// ---------------------------------------------------------------------------
template <bool ET>
__global__ __launch_bounds__(256) void vq_prep(
    const float* __restrict__ E, float* __restrict__ enorm,
    float* __restrict__ Et, unsigned* __restrict__ EbW) {
    __shared__ float sT[64][65];
    const int tid = threadIdx.x;
    const int w = tid >> 6;
    const int m64 = tid & 63;
    const int c0 = blockIdx.x * 64;

    #pragma unroll
    for (int r = 0; r < 16; ++r) {
        const int row = r * 4 + w;
        sT[row][m64] = E[row * 1024 + c0 + m64];
    }
    __syncthreads();

    if (ET) {
        #pragma unroll
        for (int it = 0; it < 16; ++it) {
            const int e = it * 256 + tid;   // 0..4095
            const int col = e >> 6, d = e & 63;
            Et[(c0 + col) * 64 + d] = sT[d][col];
        }
    }
    #pragma unroll
    for (int it = 0; it < 8; ++it) {
        const int w0 = it * 256 + tid;      // 0..2047 (u32 words)
        const int cl = w0 >> 9;             // local 16-col tile 0..3
        const int s = (w0 >> 8) & 1;
        const int ll = (w0 >> 2) & 63;
        const int j = (w0 & 3) * 2;
        const int d = s * 32 + (ll >> 4) * 8 + j;
        const int col = cl * 16 + (ll & 15);
        const unsigned lo = f2b(sT[d][col]);
        const unsigned hi = f2b(sT[d + 1][col]);
        EbW[(blockIdx.x * 4 + cl) * 512 + (w0 & 511)] = lo | (hi << 16);
    }
    if (tid < 64) {
        float s2 = 0.f;
        #pragma unroll
        for (int d = 0; d < 64; ++d) {
            float v = sT[d][tid];
            s2 = fmaf(v, v, s2);
        }
        enorm[c0 + tid] = s2;
    }
}

// ---------------------------------------------------------------------------
// Main kernel. MODE 0: Et+Eb, 1: Eb only, 2: self-contained (no ws tables).
//
// R10 RESTRUCTURE — barrier-free screening: B fragments are loaded DIRECTLY
// from the fragment-layout Eb into a 4-deep REGISTER ring (short8 pairs,
// fully unrolled loop -> static indices -> registers). No LDS staging, no
// s_barrier, no hand vmcnt: each wave is an independent pipeline; the
// compiler inserts per-register waitcnts and schedules the prefetch (issued
// 4 iterations = ~300 cyc ahead of use, > L2 latency). This removes the
// lockstep barrier+DMA convoy that R9 showed to be the stall (occupancy
// 2x'd with only -5% time). 128 rows/block (R7-proven geometry for znorm /
// re-eval / gather), grid 1024, LDS ~5.2 KB, 16 waves/CU (grid-limited).
// Packed top-2 (tile idx in low 6 mantissa bits, noise ~4e-6 << MARGIN) via
// med3+min. Exact fp32 re-eval + gather + loss: bit-exact np semantics.
// Loss: scaled partial atomicAdd straight into out[8388608] (harness zeroes
// out) — R7-proven.
// ---------------------------------------------------------------------------
template <int MODE>
__global__ __launch_bounds__(256, 4) void vq_main(
    const float* __restrict__ z, const float* __restrict__ E,
    const float* __restrict__ Et, const unsigned short* __restrict__ Eb,
    const float* __restrict__ enorm, float* __restrict__ out) {
    __shared__ float sEn[1024];
    __shared__ float sZn[128];
    __shared__ int sIdx[128];
    __shared__ float sRed[4];

    const int tid = threadIdx.x;
    const int w = tid >> 6;
    const int l = tid & 63;
    const int quad = l >> 4;
    const int m = l & 15;
    const int b = blockIdx.x;

    // enorm -> LDS (MODE<2) or compute locally (MODE 2)
    if constexpr (MODE < 2) {
        ((float4*)sEn)[tid] = ((const float4*)enorm)[tid];
    } else {
        #pragma unroll
        for (int i = 0; i < 4; ++i) {
            const int col = tid + i * 256;
            float s2 = 0.f;
            #pragma unroll
            for (int d = 0; d < 64; ++d) {
                float v = E[d * 1024 + col];
                s2 = fmaf(v, v, s2);
            }
            sEn[col] = s2;
        }
    }

    // znorm: bit-exact numpy pairwise sum (SSE path, 4 accumulators, hadd).
    if (tid < 128) {
        const float* zr = z + (b * 128 + tid) * 64;
        float S[16];
        #pragma unroll
        for (int u = 0; u < 16; ++u) { float v = zr[u]; S[u] = v * v; }
        #pragma unroll
        for (int t = 1; t < 4; ++t)
            #pragma unroll
            for (int u = 0; u < 16; ++u) {
                float v = zr[16 * t + u];
                float sq = v * v;
                S[u] = S[u] + sq;
            }
        float R0 = (S[0] + S[4]) + (S[8] + S[12]);
        float R1 = (S[1] + S[5]) + (S[9] + S[13]);
        float R2 = (S[2] + S[6]) + (S[10] + S[14]);
        float R3 = (S[3] + S[7]) + (S[11] + S[15]);
        sZn[tid] = (R0 + R1) + (R2 + R3);
    }

    // A fragments (fp32 -> bf16 RNE): wave w owns rows w*32..w*32+31
    short8 a[2][2];
    #pragma unroll
    for (int rt = 0; rt < 2; ++rt) {
        const int rowl = w * 32 + rt * 16 + m;
        #pragma unroll
        for (int s = 0; s < 2; ++s) {
            const float* zp = z + (b * 128 + rowl) * 64 + s * 32 + quad * 8;
            union { float4 v; float f[4]; } u0, u1;
            u0.v = *(const float4*)zp;
            u1.v = *(const float4*)(zp + 4);
            short8 av;
            #pragma unroll
            for (int j = 0; j < 4; ++j) av[j] = (short)f2b(u0.f[j]);
            #pragma unroll
            for (int j = 0; j < 4; ++j) av[4 + j] = (short)f2b(u1.f[j]);
            a[rt][s] = av;
        }
    }

    __syncthreads();  // sEn (and sZn) visible; the ONLY pre-tail barrier

    // packed top-2 per lane-slot: value with 16-col tile index c in low 6 bits
    float v1p[2][4], v2p[2][4];
    #pragma unroll
    for (int rt = 0; rt < 2; ++rt)
        #pragma unroll
        for (int r = 0; r < 4; ++r) { v1p[rt][r] = 3.4e38f; v2p[rt][r] = 3.4e38f; }

    if constexpr (MODE < 2) {
        // 4-deep register ring of per-lane B fragments, direct from Eb.
        // Fully unrolled -> rb indices are compile-time (registers, rule #20).
        const unsigned short* __restrict__ ebl = Eb + l * 8;
        short8 rb0[4], rb1[4];
        #pragma unroll
        for (int t = 0; t < 4; ++t) {
            rb0[t] = *(const short8*)(ebl + t * 1024);
            rb1[t] = *(const short8*)(ebl + t * 1024 + 512);
        }
        #pragma unroll
        for (int c = 0; c < 64; ++c) {
            short8 b0 = rb0[c & 3];
            short8 b1 = rb1[c & 3];
            if (c < 60) {  // prefetch tile c+4 into the slot just freed
                rb0[c & 3] = *(const short8*)(ebl + (c + 4) * 1024);
                rb1[c & 3] = *(const short8*)(ebl + (c + 4) * 1024 + 512);
            }
            f32x4 acc0 = {0.f, 0.f, 0.f, 0.f};
            f32x4 acc1 = {0.f, 0.f, 0.f, 0.f};
            acc0 = __builtin_amdgcn_mfma_f32_16x16x32_bf16(a[0][0], b0, acc0, 0, 0, 0);
            acc0 = __builtin_amdgcn_mfma_f32_16x16x32_bf16(a[0][1], b1, acc0, 0, 0, 0);
            acc1 = __builtin_amdgcn_mfma_f32_16x16x32_bf16(a[1][0], b0, acc1, 0, 0, 0);
            acc1 = __builtin_amdgcn_mfma_f32_16x16x32_bf16(a[1][1], b1, acc1, 0, 0, 0);
            const float en = sEn[c * 16 + m];
            #pragma unroll
            for (int r = 0; r < 4; ++r) {
                float p0 = fmaf(-2.f, acc0[r], en);
                p0 = __uint_as_float((__float_as_uint(p0) & 0xFFFFFFC0u) | (unsigned)c);
                v2p[0][r] = __builtin_amdgcn_fmed3f(p0, v1p[0][r], v2p[0][r]);
                v1p[0][r] = fminf(p0, v1p[0][r]);
                float p1 = fmaf(-2.f, acc1[r], en);
                p1 = __uint_as_float((__float_as_uint(p1) & 0xFFFFFFC0u) | (unsigned)c);
                v2p[1][r] = __builtin_amdgcn_fmed3f(p1, v1p[1][r], v2p[1][r]);
                v1p[1][r] = fminf(p1, v1p[1][r]);
            }
        }
    } else {
        // self-contained: build each lane's fragments directly from strided E
        // (same (d,col)->element mapping as Eb; identical f2b values).
        for (int c = 0; c < 64; ++c) {
            const int col = c * 16 + m;
            short8 b0, b1;
            #pragma unroll
            for (int j = 0; j < 8; ++j) {
                b0[j] = (short)f2b(E[(quad * 8 + j) * 1024 + col]);
                b1[j] = (short)f2b(E[(32 + quad * 8 + j) * 1024 + col]);
            }
            f32x4 acc0 = {0.f, 0.f, 0.f, 0.f};
            f32x4 acc1 = {0.f, 0.f, 0.f, 0.f};
            acc0 = __builtin_amdgcn_mfma_f32_16x16x32_bf16(a[0][0], b0, acc0, 0, 0, 0);
            acc0 = __builtin_amdgcn_mfma_f32_16x16x32_bf16(a[0][1], b1, acc0, 0, 0, 0);
            acc1 = __builtin_amdgcn_mfma_f32_16x16x32_bf16(a[1][0], b0, acc1, 0, 0, 0);
            acc1 = __builtin_amdgcn_mfma_f32_16x16x32_bf16(a[1][1], b1, acc1, 0, 0, 0);
            const float en = sEn[c * 16 + m];
            #pragma unroll
            for (int r = 0; r < 4; ++r) {
                float p0 = fmaf(-2.f, acc0[r], en);
                p0 = __uint_as_float((__float_as_uint(p0) & 0xFFFFFFC0u) | (unsigned)c);
                v2p[0][r] = __builtin_amdgcn_fmed3f(p0, v1p[0][r], v2p[0][r]);
                v1p[0][r] = fminf(p0, v1p[0][r]);
                float p1 = fmaf(-2.f, acc1[r], en);
                p1 = __uint_as_float((__float_as_uint(p1) & 0xFFFFFFC0u) | (unsigned)c);
                v2p[1][r] = __builtin_amdgcn_fmed3f(p1, v1p[1][r], v2p[1][r]);
                v1p[1][r] = fminf(p1, v1p[1][r]);
            }
        }
    }

    // exact re-evaluation (fp32 z from global, E column from Et/E);
    // lexicographic (d, k) min = np first-occurrence tie-break
    constexpr bool viaEt = (MODE == 0);
    float la = 0.f;
    #pragma unroll
    for (int rt = 0; rt < 2; ++rt) {
        #pragma unroll
        for (int r = 0; r < 4; ++r) {
            float pv1 = v1p[rt][r];
            float vb = pv1;
            #pragma unroll
            for (int mask = 1; mask <= 8; mask <<= 1)
                vb = fminf(vb, __shfl_xor(vb, mask));
            const int rowl = w * 32 + rt * 16 + quad * 4 + r;
            const float zn = sZn[rowl];
            const float* zr = z + (b * 128 + rowl) * 64;
            float d = 3.4e38f;
            int kk = 0x7fffffff;
            if (pv1 <= vb + MARGIN) {
                kk = (int)(__float_as_uint(pv1) & 63u) * 16 + m;
                d = viaEt ? np_dist<1>(zr, Et + kk * 64, zn, sEn[kk])
                          : np_dist<1024>(zr, E + kk, zn, sEn[kk]);
            }
            float pv2 = v2p[rt][r];
            if (pv2 <= vb + MARGIN) {
                int kc = (int)(__float_as_uint(pv2) & 63u) * 16 + m;
                float dd = viaEt ? np_dist<1>(zr, Et + kc * 64, zn, sEn[kc])
                                 : np_dist<1024>(zr, E + kc, zn, sEn[kc]);
                if (dd < d || (dd == d && kc < kk)) { d = dd; kk = kc; }
            }
            #pragma unroll
            for (int mask = 1; mask <= 8; mask <<= 1) {
                float d2 = __shfl_xor(d, mask);
                int c2 = __shfl_xor(kk, mask);
                bool take = (d2 < d) || (d2 == d && c2 < kk);
                d = take ? d2 : d;
                kk = take ? c2 : kk;
            }
            if (m == 0) {
                sIdx[rowl] = kk;
                la += d;
            }
        }
    }
    __syncthreads();

    // gather: 2 lanes/row, 32 dims each (contiguous from Et when available)
    {
        const int row_local = w * 32 + (l >> 1);
        const int half = l & 1;
        const int idx = sIdx[row_local];
        union { float s[32]; float4 f[8]; } tmp;
        if (viaEt) {
            const float4* src = (const float4*)(Et + idx * 64 + half * 32);
            #pragma unroll
            for (int q4 = 0; q4 < 8; ++q4) tmp.f[q4] = src[q4];
        } else {
            #pragma unroll
            for (int dd = 0; dd < 32; ++dd) tmp.s[dd] = E[(half * 32 + dd) * 1024 + idx];
        }
        float4* dst = (float4*)(out + (b * 128 + row_local) * 64 + half * 32);
        #pragma unroll
        for (int q4 = 0; q4 < 8; ++q4) dst[q4] = tmp.f[q4];
    }

    #pragma unroll
    for (int mask = 32; mask >= 1; mask >>= 1) la += __shfl_xor(la, mask);
    if (l == 0) sRed[w] = la;
    __syncthreads();

    // loss: scaled partial straight into the (harness-zeroed) out scalar.
    if (tid == 0) {
        const float blocksum = sRed[0] + sRed[1] + sRed[2] + sRed[3];
        atomicAdd(out + 8388608, blocksum * (1.25f / 8388608.f));
    }
}

extern "C" void kernel_launch(void* const* d_in, const int* in_sizes, int n_in,
                              void* d_out, int out_size, void* d_ws, size_t ws_size,
                              hipStream_t stream) {
    const float* z = (const float*)d_in[0];  // fp32 [131072,64]
    const float* E = (const float*)d_in[1];  // fp32 [64,1024]
    float* out = (float*)d_out;              // fp32 [8388609]

    char* ws = (char*)d_ws;
    float* enorm = (float*)(ws + 128);                 // 4 KB
    unsigned short* Eb = (unsigned short*)(ws + 8192); // 128 KB fragment-layout bf16
    float* Et = (float*)(ws + 139264);                 // 256 KB fp32 transpose

    if (ws_size >= (size_t)401408) {
        vq_prep<true><<<16, 256, 0, stream>>>(E, enorm, Et, (unsigned*)Eb);
        vq_main<0><<<1024, 256, 0, stream>>>(z, E, Et, Eb, enorm, out);
    } else if (ws_size >= (size_t)139264) {
        vq_prep<false><<<16, 256, 0, stream>>>(E, enorm, Et, (unsigned*)Eb);
        vq_main<1><<<1024, 256, 0, stream>>>(z, E, Et, Eb, enorm, out);
    } else {
        vq_main<2><<<1024, 256, 0, stream>>>(z, E, Et, Eb, enorm, out);
    }
}

// Round 13
// 339.929 us; speedup vs baseline: 2.8303x; 2.8303x over previous
//
#include <hip/hip_runtime.h>

#pragma clang fp contract(off)

typedef __attribute__((ext_vector_type(8))) short short8;
typedef __attribute__((ext_vector_type(4))) float f32x4;

#define MARGIN 0.02f

static __device__ __forceinline__ unsigned short f2b(float f) {
    union { float f; unsigned u; } x; x.f = f;
    unsigned u = x.u;
    return (unsigned short)((u + 0x7FFFu + ((u >> 16) & 1u)) >> 16);
}

// Bit-exact np distance: dot = single-accumulator ascending-k FMA chain
// on FULL-PRECISION fp32 z from global; d = (zn - 2*dot) + en.
// ES = element stride of the codebook column (1 for Et, 1024 for E).
template <int ES>
static __device__ __forceinline__ float np_dist(
    const float* __restrict__ zr, const float* __restrict__ ecol,
    float zn, float en) {
    float c = 0.f;
    #pragma unroll
    for (int i = 0; i < 64; ++i) c = fmaf(zr[i], ecol[i * ES], c);
    float t = zn - 2.f * c;
    return t + en;
}

// ---------------------------------------------------------------------------
// Prep kernel (grid 16 x 256) — SEPARATE LAUNCH. R6/R7/R9-proven, unchanged.
// ---------------------------------------------------------------------------
template <bool ET>
__global__ __launch_bounds__(256) void vq_prep(
    const float* __restrict__ E, float* __restrict__ enorm,
    float* __restrict__ Et, unsigned* __restrict__ EbW) {
    __shared__ float sT[64][65];
    const int tid = threadIdx.x;
    const int w = tid >> 6;
    const int m64 = tid & 63;
    const int c0 = blockIdx.x * 64;

    #pragma unroll
    for (int r = 0; r < 16; ++r) {
        const int row = r * 4 + w;
        sT[row][m64] = E[row * 1024 + c0 + m64];
    }
    __syncthreads();

    if (ET) {
        #pragma unroll
        for (int it = 0; it < 16; ++it) {
            const int e = it * 256 + tid;   // 0..4095
            const int col = e >> 6, d = e & 63;
            Et[(c0 + col) * 64 + d] = sT[d][col];
        }
    }
    #pragma unroll
    for (int it = 0; it < 8; ++it) {
        const int w0 = it * 256 + tid;      // 0..2047 (u32 words)
        const int cl = w0 >> 9;
        const int s = (w0 >> 8) & 1;
        const int ll = (w0 >> 2) & 63;
        const int j = (w0 & 3) * 2;
        const int d = s * 32 + (ll >> 4) * 8 + j;
        const int col = cl * 16 + (ll & 15);
        const unsigned lo = f2b(sT[d][col]);
        const unsigned hi = f2b(sT[d + 1][col]);
        EbW[(blockIdx.x * 4 + cl) * 512 + (w0 & 511)] = lo | (hi << 16);
    }
    if (tid < 64) {
        float s2 = 0.f;
        #pragma unroll
        for (int d = 0; d < 64; ++d) {
            float v = sT[d][tid];
            s2 = fmaf(v, v, s2);
        }
        enorm[c0 + tid] = s2;
    }
}

// ---------------------------------------------------------------------------
// Main kernel — EXACT R9 structure (proven 74 µs) carved by PART for the
// ablation. PART 0: full real kernel (runs LAST, owns out + loss).
// PART 1: front + screening only; keep-alive reduce of v1p/v2p -> probe
//         scratch atomic; early return (no tail).
// PART 2: front + tail only; screening replaced by synthetic spread-out
//         v1p/v2p (x100 scaling -> ~1 passing lane -> ~2 np_dist per r,
//         matching the real path's load); gather writes out rows that
//         PART 0 later overwrites; loss -> probe scratch (NOT out).
// front = dur(1) + dur(2) - dur(0) by construction.
// 64 rows/block, grid 2048, LDS exactly 20480 B, 8 blocks/CU (R9-proven).
// ---------------------------------------------------------------------------
template <int MODE, int PART>
__global__ __launch_bounds__(256, 8) void vq_main(
    const float* __restrict__ z, const float* __restrict__ E,
    const float* __restrict__ Et, const unsigned short* __restrict__ Eb,
    const float* __restrict__ enorm, float* __restrict__ out,
    float* __restrict__ probe) {
    __shared__ unsigned short sB[2][4096];  // 2 x 8 KB B half-tiles
    __shared__ float sEn[1024];             // total static LDS = 20480 B

    // overlays (valid only AFTER the screening loop; sB[0] is dead then)
    float* sZn = (float*)&sB[0][0];
    int* sIdx = (int*)((char*)&sB[0][0] + 256);
    float* sRed = (float*)((char*)&sB[0][0] + 512);

    const int tid = threadIdx.x;
    const int w = tid >> 6;
    const int l = tid & 63;
    const int quad = l >> 4;
    const int m = l & 15;
    const int b = blockIdx.x;

    // half-tile h = 8 KB of Eb; wave w stages its 2 KB (= 16-col tile ct=w)
    auto stage = [&](int h, int buf) {
        const unsigned short* gp = Eb + h * 4096 + w * 1024 + l * 8;
        unsigned short* lp = &sB[buf][w * 1024];
        #pragma unroll
        for (int i = 0; i < 2; ++i) {
            __builtin_amdgcn_global_load_lds(
                (const __attribute__((address_space(1))) void*)(gp + i * 512),
                (__attribute__((address_space(3))) void*)(lp + i * 512),
                16, 0, 0);
        }
    };

    if constexpr (MODE < 2) {
        if constexpr (PART != 2) {
            stage(0, 0);   // DMA latency hides under sEn + A-fragment loads
            stage(1, 1);
        }
        ((float4*)sEn)[tid] = ((const float4*)enorm)[tid];
    } else {
        #pragma unroll
        for (int i = 0; i < 4; ++i) {
            const int col = tid + i * 256;
            float s2 = 0.f;
            #pragma unroll
            for (int d = 0; d < 64; ++d) {
                float v = E[d * 1024 + col];
                s2 = fmaf(v, v, s2);
            }
            sEn[col] = s2;
        }
    }

    // A fragments (fp32 -> bf16 RNE): wave w owns rows w*16..w*16+15
    short8 a[2];
    {
        const int rowl = w * 16 + m;
        #pragma unroll
        for (int s = 0; s < 2; ++s) {
            const float* zp = z + (b * 64 + rowl) * 64 + s * 32 + quad * 8;
            union { float4 v; float f[4]; } u0, u1;
            u0.v = *(const float4*)zp;
            u1.v = *(const float4*)(zp + 4);
            short8 av;
            #pragma unroll
            for (int j = 0; j < 4; ++j) av[j] = (short)f2b(u0.f[j]);
            #pragma unroll
            for (int j = 0; j < 4; ++j) av[4 + j] = (short)f2b(u1.f[j]);
            a[s] = av;
        }
    }

    // packed top-2 per lane: value with 16-col tile index c in low 6 bits
    float v1p[4], v2p[4];
    #pragma unroll
    for (int r = 0; r < 4; ++r) { v1p[r] = 3.4e38f; v2p[r] = 3.4e38f; }

    if constexpr (PART == 2) {
        // keep the A-fragment loads live (rule #17: anti-DCE)
        int ka = 0;
        #pragma unroll
        for (int s = 0; s < 2; ++s)
            #pragma unroll
            for (int j = 0; j < 8; ++j) ka ^= (int)a[s][j];
        asm volatile("" :: "v"(ka));
        __syncthreads();  // sEn visible
        // synthetic screening result: spread x100 so ~1 lane passes margin
        // -> ~2 np_dist per r (matches the real path's typical load)
        #pragma unroll
        for (int r = 0; r < 4; ++r) {
            const float base = sEn[(((m * 4 + r) * 16) + quad) & 1023] * 100.0f;
            const unsigned cc = (unsigned)(m * 4 + r);
            v1p[r] = __uint_as_float((__float_as_uint(base) & 0xFFFFFFC0u) | cc);
            v2p[r] = __uint_as_float((__float_as_uint(base) & 0xFFFFFFC0u) | ((cc + 1) & 63u));
        }
    } else if constexpr (MODE < 2) {
        // R9-proven block-wide choreography, verbatim
        asm volatile("s_waitcnt vmcnt(2) lgkmcnt(0)" ::: "memory");
        __builtin_amdgcn_sched_barrier(0);
        __builtin_amdgcn_s_barrier();

        for (int h = 0; h < 16; ++h) {
            const unsigned short* bufp = &sB[h & 1][l * 8];
            #pragma unroll
            for (int ct = 0; ct < 4; ++ct) {
                const int c = h * 4 + ct;
                short8 b0 = *(const short8*)(bufp + ct * 1024);
                short8 b1 = *(const short8*)(bufp + ct * 1024 + 512);
                f32x4 acc = {0.f, 0.f, 0.f, 0.f};
                acc = __builtin_amdgcn_mfma_f32_16x16x32_bf16(a[0], b0, acc, 0, 0, 0);
                acc = __builtin_amdgcn_mfma_f32_16x16x32_bf16(a[1], b1, acc, 0, 0, 0);
                const float en = sEn[c * 16 + m];
                #pragma unroll
                for (int r = 0; r < 4; ++r) {
                    float p0 = fmaf(-2.f, acc[r], en);
                    p0 = __uint_as_float((__float_as_uint(p0) & 0xFFFFFFC0u) | (unsigned)c);
                    v2p[r] = __builtin_amdgcn_fmed3f(p0, v1p[r], v2p[r]);
                    v1p[r] = fminf(p0, v1p[r]);
                }
            }
            if (h == 15) break;
            __builtin_amdgcn_s_barrier();
            if (h < 14) {
                stage(h + 2, h & 1);
                asm volatile("s_waitcnt vmcnt(2)" ::: "memory");
            } else {
                asm volatile("s_waitcnt vmcnt(0)" ::: "memory");
            }
            __builtin_amdgcn_sched_barrier(0);
            __builtin_amdgcn_s_barrier();
        }
    } else {
        // self-contained conversion path (R9 verbatim)
        unsigned* sW = (unsigned*)&sB[0][0];
        __syncthreads();
        for (int h = 0; h < 16; ++h) {
            #pragma unroll
            for (int it = 0; it < 8; ++it) {
                const int w0 = it * 256 + tid;
                const int cl = w0 >> 9;
                const int s = (w0 >> 8) & 1;
                const int ll = (w0 >> 2) & 63;
                const int j = (w0 & 3) * 2;
                const int d = s * 32 + (ll >> 4) * 8 + j;
                const int col = (h * 4 + cl) * 16 + (ll & 15);
                const unsigned lo = f2b(E[d * 1024 + col]);
                const unsigned hi = f2b(E[(d + 1) * 1024 + col]);
                sW[w0] = lo | (hi << 16);
            }
            __syncthreads();
            const unsigned short* bufp = &sB[0][l * 8];
            #pragma unroll
            for (int ct = 0; ct < 4; ++ct) {
                const int c = h * 4 + ct;
                short8 b0 = *(const short8*)(bufp + ct * 1024);
                short8 b1 = *(const short8*)(bufp + ct * 1024 + 512);
                f32x4 acc = {0.f, 0.f, 0.f, 0.f};
                acc = __builtin_amdgcn_mfma_f32_16x16x32_bf16(a[0], b0, acc, 0, 0, 0);
                acc = __builtin_amdgcn_mfma_f32_16x16x32_bf16(a[1], b1, acc, 0, 0, 0);
                const float en = sEn[c * 16 + m];
                #pragma unroll
                for (int r = 0; r < 4; ++r) {
                    float p0 = fmaf(-2.f, acc[r], en);
                    p0 = __uint_as_float((__float_as_uint(p0) & 0xFFFFFFC0u) | (unsigned)c);
                    v2p[r] = __builtin_amdgcn_fmed3f(p0, v1p[r], v2p[r]);
                    v1p[r] = fminf(p0, v1p[r]);
                }
            }
            __syncthreads();
        }
    }

    if constexpr (PART == 1) {
        // keep the whole screening dependency chain live, then stop
        float s = 0.f;
        #pragma unroll
        for (int r = 0; r < 4; ++r) s += v1p[r] + v2p[r];
        #pragma unroll
        for (int mask = 1; mask <= 32; mask <<= 1) s += __shfl_xor(s, mask);
        if (l == 0) atomicAdd(probe, s);
        return;
    }

    __syncthreads();  // all waves done with sB -> overlays safe

    // znorm (post-screening; overlay in dead sB space):
    // bit-exact numpy pairwise sum (SSE path, 4 accumulators, hadd).
    if (tid < 64) {
        const float* zr = z + (b * 64 + tid) * 64;
        float S[16];
        #pragma unroll
        for (int u = 0; u < 16; ++u) { float v = zr[u]; S[u] = v * v; }
        #pragma unroll
        for (int t = 1; t < 4; ++t)
            #pragma unroll
            for (int u = 0; u < 16; ++u) {
                float v = zr[16 * t + u];
                float sq = v * v;
                S[u] = S[u] + sq;
            }
        float R0 = (S[0] + S[4]) + (S[8] + S[12]);
        float R1 = (S[1] + S[5]) + (S[9] + S[13]);
        float R2 = (S[2] + S[6]) + (S[10] + S[14]);
        float R3 = (S[3] + S[7]) + (S[11] + S[15]);
        sZn[tid] = (R0 + R1) + (R2 + R3);
    }
    __syncthreads();

    // exact re-evaluation (fp32 z from global, E column from Et/E);
    // lexicographic (d, k) min = np first-occurrence tie-break
    constexpr bool viaEt = (MODE == 0);
    float la = 0.f;
    #pragma unroll
    for (int r = 0; r < 4; ++r) {
        float pv1 = v1p[r];
        float vb = pv1;
        #pragma unroll
        for (int mask = 1; mask <= 8; mask <<= 1)
            vb = fminf(vb, __shfl_xor(vb, mask));
        const int rowl = w * 16 + quad * 4 + r;
        const float zn = sZn[rowl];
        const float* zr = z + (b * 64 + rowl) * 64;
        float d = 3.4e38f;
        int kk = 0x7fffffff;
        if (pv1 <= vb + MARGIN) {
            kk = (int)(__float_as_uint(pv1) & 63u) * 16 + m;
            d = viaEt ? np_dist<1>(zr, Et + kk * 64, zn, sEn[kk])
                      : np_dist<1024>(zr, E + kk, zn, sEn[kk]);
        }
        float pv2 = v2p[r];
        if (pv2 <= vb + MARGIN) {
            int kc = (int)(__float_as_uint(pv2) & 63u) * 16 + m;
            float dd = viaEt ? np_dist<1>(zr, Et + kc * 64, zn, sEn[kc])
                             : np_dist<1024>(zr, E + kc, zn, sEn[kc]);
            if (dd < d || (dd == d && kc < kk)) { d = dd; kk = kc; }
        }
        #pragma unroll
        for (int mask = 1; mask <= 8; mask <<= 1) {
            float d2 = __shfl_xor(d, mask);
            int c2 = __shfl_xor(kk, mask);
            bool take = (d2 < d) || (d2 == d && c2 < kk);
            d = take ? d2 : d;
            kk = take ? c2 : kk;
        }
        if (m == 0) {
            sIdx[rowl] = kk;
            la += d;
        }
    }
    __syncthreads();

    // gather: 4 lanes/row, 16 dims each (contiguous from Et when available)
    {
        const int row_local = w * 16 + (l >> 2);
        const int part = l & 3;
        const int idx = sIdx[row_local];
        union { float s[16]; float4 f[4]; } tmp;
        if (viaEt) {
            const float4* src = (const float4*)(Et + idx * 64 + part * 16);
            #pragma unroll
            for (int q4 = 0; q4 < 4; ++q4) tmp.f[q4] = src[q4];
        } else {
            #pragma unroll
            for (int dd = 0; dd < 16; ++dd) tmp.s[dd] = E[(part * 16 + dd) * 1024 + idx];
        }
        float4* dst = (float4*)(out + (b * 64 + row_local) * 64 + part * 16);
        #pragma unroll
        for (int q4 = 0; q4 < 4; ++q4) dst[q4] = tmp.f[q4];
    }

    #pragma unroll
    for (int mask = 32; mask >= 1; mask >>= 1) la += __shfl_xor(la, mask);
    if (l == 0) sRed[w] = la;
    __syncthreads();

    if (tid == 0) {
        const float blocksum = sRed[0] + sRed[1] + sRed[2] + sRed[3];
        if constexpr (PART == 0) {
            // real loss into the (harness-zeroed) out scalar
            atomicAdd(out + 8388608, blocksum * (1.25f / 8388608.f));
        } else {
            // probe: keep tail live without touching out's loss scalar
            atomicAdd(probe, blocksum);
        }
    }
}

extern "C" void kernel_launch(void* const* d_in, const int* in_sizes, int n_in,
                              void* d_out, int out_size, void* d_ws, size_t ws_size,
                              hipStream_t stream) {
    const float* z = (const float*)d_in[0];  // fp32 [131072,64]
    const float* E = (const float*)d_in[1];  // fp32 [64,1024]
    float* out = (float*)d_out;              // fp32 [8388609]

    char* ws = (char*)d_ws;
    float* probe = (float*)ws;                         // 4 B scratch (unchecked)
    float* enorm = (float*)(ws + 128);                 // 4 KB
    unsigned short* Eb = (unsigned short*)(ws + 8192); // 128 KB fragment-layout bf16
    float* Et = (float*)(ws + 139264);                 // 256 KB fp32 transpose

    if (ws_size >= (size_t)401408) {
        vq_prep<true><<<16, 256, 0, stream>>>(E, enorm, Et, (unsigned*)Eb);
        // ablation probes (diagnostic; outputs overwritten / sunk to ws)
        vq_main<0, 1><<<2048, 256, 0, stream>>>(z, E, Et, Eb, enorm, out, probe);
        vq_main<0, 2><<<2048, 256, 0, stream>>>(z, E, Et, Eb, enorm, out, probe);
        // real kernel LAST: owns out rows + loss scalar
        vq_main<0, 0><<<2048, 256, 0, stream>>>(z, E, Et, Eb, enorm, out, probe);
    } else if (ws_size >= (size_t)139264) {
        vq_prep<false><<<16, 256, 0, stream>>>(E, enorm, Et, (unsigned*)Eb);
        vq_main<1, 0><<<2048, 256, 0, stream>>>(z, E, Et, Eb, enorm, out, probe);
    } else {
        vq_main<2, 0><<<2048, 256, 0, stream>>>(z, E, Et, Eb, enorm, out, probe);
    }
}

// Round 14
// 145.171 us; speedup vs baseline: 6.6273x; 2.3416x over previous
//
#include <hip/hip_runtime.h>

#pragma clang fp contract(off)

typedef __attribute__((ext_vector_type(8))) short short8;
typedef __attribute__((ext_vector_type(4))) float f32x4;

#define MARGIN 0.02f

static __device__ __forceinline__ unsigned short f2b(float f) {
    union { float f; unsigned u; } x; x.f = f;
    unsigned u = x.u;
    return (unsigned short)((u + 0x7FFFu + ((u >> 16) & 1u)) >> 16);
}

// Bit-exact np distance: dot = single-accumulator ascending-k FMA chain
// on FULL-PRECISION fp32 z from global; d = (zn - 2*dot) + en.
// ES = element stride of the codebook column (1 for Et, 1024 for E).
template <int ES>
static __device__ __forceinline__ float np_dist(
    const float* __restrict__ zr, const float* __restrict__ ecol,
    float zn, float en) {
    float c = 0.f;
    #pragma unroll
    for (int i = 0; i < 64; ++i) c = fmaf(zr[i], ecol[i * ES], c);
    float t = zn - 2.f * c;
    return t + en;
}

// ---------------------------------------------------------------------------
// Prep kernel (grid 16 x 256) — SEPARATE LAUNCH. R6/R7/R9-proven, unchanged.
// ---------------------------------------------------------------------------
template <bool ET>
__global__ __launch_bounds__(256) void vq_prep(
    const float* __restrict__ E, float* __restrict__ enorm,
    float* __restrict__ Et, unsigned* __restrict__ EbW) {
    __shared__ float sT[64][65];
    const int tid = threadIdx.x;
    const int w = tid >> 6;
    const int m64 = tid & 63;
    const int c0 = blockIdx.x * 64;

    #pragma unroll
    for (int r = 0; r < 16; ++r) {
        const int row = r * 4 + w;
        sT[row][m64] = E[row * 1024 + c0 + m64];
    }
    __syncthreads();

    if (ET) {
        #pragma unroll
        for (int it = 0; it < 16; ++it) {
            const int e = it * 256 + tid;   // 0..4095
            const int col = e >> 6, d = e & 63;
            Et[(c0 + col) * 64 + d] = sT[d][col];
        }
    }
    #pragma unroll
    for (int it = 0; it < 8; ++it) {
        const int w0 = it * 256 + tid;      // 0..2047 (u32 words)
        const int cl = w0 >> 9;
        const int s = (w0 >> 8) & 1;
        const int ll = (w0 >> 2) & 63;
        const int j = (w0 & 3) * 2;
        const int d = s * 32 + (ll >> 4) * 8 + j;
        const int col = cl * 16 + (ll & 15);
        const unsigned lo = f2b(sT[d][col]);
        const unsigned hi = f2b(sT[d + 1][col]);
        EbW[(blockIdx.x * 4 + cl) * 512 + (w0 & 511)] = lo | (hi << 16);
    }
    if (tid < 64) {
        float s2 = 0.f;
        #pragma unroll
        for (int d = 0; d < 64; ++d) {
            float v = sT[d][tid];
            s2 = fmaf(v, v, s2);
        }
        enorm[c0 + tid] = s2;
    }
}

// ---------------------------------------------------------------------------
// Main kernel. MODE 0: Et+Eb, 1: Eb only, 2: self-contained (no ws tables).
//
// R14 = R9-proven structure + two issue-count reductions:
//  (a) NEGATED-A screening: A fragments carry bf16(-z) (sign-bit flip,
//      exact) and the MFMA accumulator is INITIALIZED with en/2 (sEn now
//      stores enorm*0.5 — exact power-of-2 scaling). The MFMA directly
//      yields q = en/2 - dot = d_screen/2: same ordering, margin compare
//      at +MARGIN/2. Deletes the per-value post-MFMA fmaf and the
//      post-MFMA en dependency. Re-eval stays bit-exact (en = 2*sEn).
//  (b) znorm spread across all 4 waves (lanes 0-15 each, 16 rows/wave)
//      instead of wave 0 doing all 64 rows while 3 waves idle.
// Screening choreography, tail, gather, loss: R9-verbatim (proven).
// 64 rows/block, grid 2048, LDS exactly 20480 B, 8 blocks/CU.
// Packed top-2 (tile idx in low 6 mantissa bits, noise << margin) via
// med3+min. Loss: scaled partial atomicAdd into out[8388608].
// ---------------------------------------------------------------------------
template <int MODE>
__global__ __launch_bounds__(256, 8) void vq_main(
    const float* __restrict__ z, const float* __restrict__ E,
    const float* __restrict__ Et, const unsigned short* __restrict__ Eb,
    const float* __restrict__ enorm, float* __restrict__ out) {
    __shared__ unsigned short sB[2][4096];  // 2 x 8 KB B half-tiles
    __shared__ float sEn[1024];             // holds enorm*0.5; 20480 B total

    // overlays (valid only AFTER the screening loop; sB[0] is dead then)
    float* sZn = (float*)&sB[0][0];
    int* sIdx = (int*)((char*)&sB[0][0] + 256);
    float* sRed = (float*)((char*)&sB[0][0] + 512);

    const int tid = threadIdx.x;
    const int w = tid >> 6;
    const int l = tid & 63;
    const int quad = l >> 4;
    const int m = l & 15;
    const int b = blockIdx.x;

    // half-tile h = 8 KB of Eb; wave w stages its 2 KB (= 16-col tile ct=w)
    auto stage = [&](int h, int buf) {
        const unsigned short* gp = Eb + h * 4096 + w * 1024 + l * 8;
        unsigned short* lp = &sB[buf][w * 1024];
        #pragma unroll
        for (int i = 0; i < 2; ++i) {
            __builtin_amdgcn_global_load_lds(
                (const __attribute__((address_space(1))) void*)(gp + i * 512),
                (__attribute__((address_space(3))) void*)(lp + i * 512),
                16, 0, 0);
        }
    };

    if constexpr (MODE < 2) {
        stage(0, 0);   // DMA latency hides under sEn + A-fragment loads
        stage(1, 1);
        float4 e4 = ((const float4*)enorm)[tid];
        e4.x *= 0.5f; e4.y *= 0.5f; e4.z *= 0.5f; e4.w *= 0.5f;
        ((float4*)sEn)[tid] = e4;   // sEn = enorm/2 (exact)
    } else {
        #pragma unroll
        for (int i = 0; i < 4; ++i) {
            const int col = tid + i * 256;
            float s2 = 0.f;
            #pragma unroll
            for (int d = 0; d < 64; ++d) {
                float v = E[d * 1024 + col];
                s2 = fmaf(v, v, s2);
            }
            sEn[col] = s2 * 0.5f;   // enorm/2 (exact)
        }
    }

    // A fragments: bf16 RNE of -z (sign-bit flip of bf16(z), exact).
    // Wave w owns rows w*16..w*16+15.
    short8 a[2];
    {
        const int rowl = w * 16 + m;
        #pragma unroll
        for (int s = 0; s < 2; ++s) {
            const float* zp = z + (b * 64 + rowl) * 64 + s * 32 + quad * 8;
            union { float4 v; float f[4]; } u0, u1;
            u0.v = *(const float4*)zp;
            u1.v = *(const float4*)(zp + 4);
            short8 av;
            #pragma unroll
            for (int j = 0; j < 4; ++j) av[j] = (short)(f2b(u0.f[j]) ^ 0x8000u);
            #pragma unroll
            for (int j = 0; j < 4; ++j) av[4 + j] = (short)(f2b(u1.f[j]) ^ 0x8000u);
            a[s] = av;
        }
    }

    // packed top-2 per lane: q-value with 16-col tile index c in low 6 bits
    float v1p[4], v2p[4];
    #pragma unroll
    for (int r = 0; r < 4; ++r) { v1p[r] = 3.4e38f; v2p[r] = 3.4e38f; }

    if constexpr (MODE < 2) {
        // R9-proven block-wide choreography, verbatim
        asm volatile("s_waitcnt vmcnt(2) lgkmcnt(0)" ::: "memory");
        __builtin_amdgcn_sched_barrier(0);
        __builtin_amdgcn_s_barrier();

        for (int h = 0; h < 16; ++h) {
            const unsigned short* bufp = &sB[h & 1][l * 8];
            #pragma unroll
            for (int ct = 0; ct < 4; ++ct) {
                const int c = h * 4 + ct;
                short8 b0 = *(const short8*)(bufp + ct * 1024);
                short8 b1 = *(const short8*)(bufp + ct * 1024 + 512);
                const float enh = sEn[c * 16 + m];
                f32x4 acc = {enh, enh, enh, enh};   // q = en/2 - dot
                acc = __builtin_amdgcn_mfma_f32_16x16x32_bf16(a[0], b0, acc, 0, 0, 0);
                acc = __builtin_amdgcn_mfma_f32_16x16x32_bf16(a[1], b1, acc, 0, 0, 0);
                #pragma unroll
                for (int r = 0; r < 4; ++r) {
                    float p0 = __uint_as_float(
                        (__float_as_uint(acc[r]) & 0xFFFFFFC0u) | (unsigned)c);
                    v2p[r] = __builtin_amdgcn_fmed3f(p0, v1p[r], v2p[r]);
                    v1p[r] = fminf(p0, v1p[r]);
                }
            }
            if (h == 15) break;
            __builtin_amdgcn_s_barrier();
            if (h < 14) {
                stage(h + 2, h & 1);
                asm volatile("s_waitcnt vmcnt(2)" ::: "memory");
            } else {
                asm volatile("s_waitcnt vmcnt(0)" ::: "memory");
            }
            __builtin_amdgcn_sched_barrier(0);
            __builtin_amdgcn_s_barrier();
        }
    } else {
        // self-contained: convert E -> fragment layout in LDS per half-tile
        unsigned* sW = (unsigned*)&sB[0][0];
        __syncthreads();
        for (int h = 0; h < 16; ++h) {
            #pragma unroll
            for (int it = 0; it < 8; ++it) {
                const int w0 = it * 256 + tid;
                const int cl = w0 >> 9;
                const int s = (w0 >> 8) & 1;
                const int ll = (w0 >> 2) & 63;
                const int j = (w0 & 3) * 2;
                const int d = s * 32 + (ll >> 4) * 8 + j;
                const int col = (h * 4 + cl) * 16 + (ll & 15);
                const unsigned lo = f2b(E[d * 1024 + col]);
                const unsigned hi = f2b(E[(d + 1) * 1024 + col]);
                sW[w0] = lo | (hi << 16);
            }
            __syncthreads();
            const unsigned short* bufp = &sB[0][l * 8];
            #pragma unroll
            for (int ct = 0; ct < 4; ++ct) {
                const int c = h * 4 + ct;
                short8 b0 = *(const short8*)(bufp + ct * 1024);
                short8 b1 = *(const short8*)(bufp + ct * 1024 + 512);
                const float enh = sEn[c * 16 + m];
                f32x4 acc = {enh, enh, enh, enh};
                acc = __builtin_amdgcn_mfma_f32_16x16x32_bf16(a[0], b0, acc, 0, 0, 0);
                acc = __builtin_amdgcn_mfma_f32_16x16x32_bf16(a[1], b1, acc, 0, 0, 0);
                #pragma unroll
                for (int r = 0; r < 4; ++r) {
                    float p0 = __uint_as_float(
                        (__float_as_uint(acc[r]) & 0xFFFFFFC0u) | (unsigned)c);
                    v2p[r] = __builtin_amdgcn_fmed3f(p0, v1p[r], v2p[r]);
                    v1p[r] = fminf(p0, v1p[r]);
                }
            }
            __syncthreads();
        }
    }

    __syncthreads();  // all waves done with sB -> overlays safe

    // znorm (post-screening; overlay in dead sB space), 4x parallel:
    // lanes 0-15 of each wave, 16 rows/wave. Per-row bit-exact numpy
    // pairwise sum (SSE path, 4 accumulators, hadd) — order unchanged.
    if (l < 16) {
        const int row = w * 16 + l;
        const float* zr = z + (b * 64 + row) * 64;
        float S[16];
        #pragma unroll
        for (int u = 0; u < 16; ++u) { float v = zr[u]; S[u] = v * v; }
        #pragma unroll
        for (int t = 1; t < 4; ++t)
            #pragma unroll
            for (int u = 0; u < 16; ++u) {
                float v = zr[16 * t + u];
                float sq = v * v;
                S[u] = S[u] + sq;
            }
        float R0 = (S[0] + S[4]) + (S[8] + S[12]);
        float R1 = (S[1] + S[5]) + (S[9] + S[13]);
        float R2 = (S[2] + S[6]) + (S[10] + S[14]);
        float R3 = (S[3] + S[7]) + (S[11] + S[15]);
        sZn[row] = (R0 + R1) + (R2 + R3);
    }
    __syncthreads();

    // exact re-evaluation (fp32 z from global, E column from Et/E);
    // en = 2*sEn (exact); lexicographic (d,k) min = np first-occurrence.
    constexpr bool viaEt = (MODE == 0);
    const float margin_q = MARGIN * 0.5f;   // q-space margin (q = d/2)
    float la = 0.f;
    #pragma unroll
    for (int r = 0; r < 4; ++r) {
        float pv1 = v1p[r];
        float vb = pv1;
        #pragma unroll
        for (int mask = 1; mask <= 8; mask <<= 1)
            vb = fminf(vb, __shfl_xor(vb, mask));
        const int rowl = w * 16 + quad * 4 + r;
        const float zn = sZn[rowl];
        const float* zr = z + (b * 64 + rowl) * 64;
        float d = 3.4e38f;
        int kk = 0x7fffffff;
        if (pv1 <= vb + margin_q) {
            kk = (int)(__float_as_uint(pv1) & 63u) * 16 + m;
            d = viaEt ? np_dist<1>(zr, Et + kk * 64, zn, 2.f * sEn[kk])
                      : np_dist<1024>(zr, E + kk, zn, 2.f * sEn[kk]);
        }
        float pv2 = v2p[r];
        if (pv2 <= vb + margin_q) {
            int kc = (int)(__float_as_uint(pv2) & 63u) * 16 + m;
            float dd = viaEt ? np_dist<1>(zr, Et + kc * 64, zn, 2.f * sEn[kc])
                             : np_dist<1024>(zr, E + kc, zn, 2.f * sEn[kc]);
            if (dd < d || (dd == d && kc < kk)) { d = dd; kk = kc; }
        }
        #pragma unroll
        for (int mask = 1; mask <= 8; mask <<= 1) {
            float d2 = __shfl_xor(d, mask);
            int c2 = __shfl_xor(kk, mask);
            bool take = (d2 < d) || (d2 == d && c2 < kk);
            d = take ? d2 : d;
            kk = take ? c2 : kk;
        }
        if (m == 0) {
            sIdx[rowl] = kk;
            la += d;
        }
    }
    __syncthreads();

    // gather: 4 lanes/row, 16 dims each (contiguous from Et when available)
    {
        const int row_local = w * 16 + (l >> 2);
        const int part = l & 3;
        const int idx = sIdx[row_local];
        union { float s[16]; float4 f[4]; } tmp;
        if (viaEt) {
            const float4* src = (const float4*)(Et + idx * 64 + part * 16);
            #pragma unroll
            for (int q4 = 0; q4 < 4; ++q4) tmp.f[q4] = src[q4];
        } else {
            #pragma unroll
            for (int dd = 0; dd < 16; ++dd) tmp.s[dd] = E[(part * 16 + dd) * 1024 + idx];
        }
        float4* dst = (float4*)(out + (b * 64 + row_local) * 64 + part * 16);
        #pragma unroll
        for (int q4 = 0; q4 < 4; ++q4) dst[q4] = tmp.f[q4];
    }

    #pragma unroll
    for (int mask = 32; mask >= 1; mask >>= 1) la += __shfl_xor(la, mask);
    if (l == 0) sRed[w] = la;
    __syncthreads();

    // loss: scaled partial straight into the (harness-zeroed) out scalar.
    if (tid == 0) {
        const float blocksum = sRed[0] + sRed[1] + sRed[2] + sRed[3];
        atomicAdd(out + 8388608, blocksum * (1.25f / 8388608.f));
    }
}

extern "C" void kernel_launch(void* const* d_in, const int* in_sizes, int n_in,
                              void* d_out, int out_size, void* d_ws, size_t ws_size,
                              hipStream_t stream) {
    const float* z = (const float*)d_in[0];  // fp32 [131072,64]
    const float* E = (const float*)d_in[1];  // fp32 [64,1024]
    float* out = (float*)d_out;              // fp32 [8388609]

    char* ws = (char*)d_ws;
    float* enorm = (float*)(ws + 128);                 // 4 KB
    unsigned short* Eb = (unsigned short*)(ws + 8192); // 128 KB fragment-layout bf16
    float* Et = (float*)(ws + 139264);                 // 256 KB fp32 transpose

    if (ws_size >= (size_t)401408) {
        vq_prep<true><<<16, 256, 0, stream>>>(E, enorm, Et, (unsigned*)Eb);
        vq_main<0><<<2048, 256, 0, stream>>>(z, E, Et, Eb, enorm, out);
    } else if (ws_size >= (size_t)139264) {
        vq_prep<false><<<16, 256, 0, stream>>>(E, enorm, Et, (unsigned*)Eb);
        vq_main<1><<<2048, 256, 0, stream>>>(z, E, Et, Eb, enorm, out);
    } else {
        vq_main<2><<<2048, 256, 0, stream>>>(z, E, Et, Eb, enorm, out);
    }
}

// Round 15
// 143.054 us; speedup vs baseline: 6.7254x; 1.0148x over previous
//
#include <hip/hip_runtime.h>

#pragma clang fp contract(off)

typedef __attribute__((ext_vector_type(8))) short short8;
typedef __attribute__((ext_vector_type(4))) float f32x4;

#define MARGIN 0.02f

static __device__ __forceinline__ unsigned short f2b(float f) {
    union { float f; unsigned u; } x; x.f = f;
    unsigned u = x.u;
    return (unsigned short)((u + 0x7FFFu + ((u >> 16) & 1u)) >> 16);
}

// Bit-exact np distance: dot = single-accumulator ascending-k FMA chain
// on FULL-PRECISION fp32 z from global; d = (zn - 2*dot) + en.
// ES = element stride of the codebook column (1 for Et, 1024 for E).
template <int ES>
static __device__ __forceinline__ float np_dist(
    const float* __restrict__ zr, const float* __restrict__ ecol,
    float zn, float en) {
    float c = 0.f;
    #pragma unroll
    for (int i = 0; i < 64; ++i) c = fmaf(zr[i], ecol[i * ES], c);
    float t = zn - 2.f * c;
    return t + en;
}

// ---------------------------------------------------------------------------
// Prep kernel (grid 16 x 256) — SEPARATE LAUNCH. R6..R14-proven, unchanged.
// ---------------------------------------------------------------------------
template <bool ET>
__global__ __launch_bounds__(256) void vq_prep(
    const float* __restrict__ E, float* __restrict__ enorm,
    float* __restrict__ Et, unsigned* __restrict__ EbW) {
    __shared__ float sT[64][65];
    const int tid = threadIdx.x;
    const int w = tid >> 6;
    const int m64 = tid & 63;
    const int c0 = blockIdx.x * 64;

    #pragma unroll
    for (int r = 0; r < 16; ++r) {
        const int row = r * 4 + w;
        sT[row][m64] = E[row * 1024 + c0 + m64];
    }
    __syncthreads();

    if (ET) {
        #pragma unroll
        for (int it = 0; it < 16; ++it) {
            const int e = it * 256 + tid;   // 0..4095
            const int col = e >> 6, d = e & 63;
            Et[(c0 + col) * 64 + d] = sT[d][col];
        }
    }
    #pragma unroll
    for (int it = 0; it < 8; ++it) {
        const int w0 = it * 256 + tid;      // 0..2047 (u32 words)
        const int cl = w0 >> 9;
        const int s = (w0 >> 8) & 1;
        const int ll = (w0 >> 2) & 63;
        const int j = (w0 & 3) * 2;
        const int d = s * 32 + (ll >> 4) * 8 + j;
        const int col = cl * 16 + (ll & 15);
        const unsigned lo = f2b(sT[d][col]);
        const unsigned hi = f2b(sT[d + 1][col]);
        EbW[(blockIdx.x * 4 + cl) * 512 + (w0 & 511)] = lo | (hi << 16);
    }
    if (tid < 64) {
        float s2 = 0.f;
        #pragma unroll
        for (int d = 0; d < 64; ++d) {
            float v = sT[d][tid];
            s2 = fmaf(v, v, s2);
        }
        enorm[c0 + tid] = s2;
    }
}

// ---------------------------------------------------------------------------
// Main kernel. MODE 0: Et+Eb, 1: Eb only, 2: self-contained.
//
// R15 RESTRUCTURE — stage once, barrier almost never:
//  - Block = 512 threads (8 waves), grid 512; wave owns 32 rows (2 strips).
//  - LDS: sB = 64 KB HALF-codebook (32 tiles, fragment layout) + sEn 4 KB
//    + per-wave sIdx + sRed ≈ 69 KB -> 2 blocks/CU (16 waves/CU).
//  - Two staging phases per block (half 0, half 1): each wave DMAs its 8 KB
//    slice once via global_load_lds; vmcnt(0)+barrier; then the screening
//    loop has NO barriers and NO waitcnts at all — pure ds_read+MFMA+select
//    with ds_reads SHARED by both strips (2 ds_read feed 4 MFMA).
//    4 barriers/block total (vs 48 in R14); staging traffic 256->64 MB.
//  - Tail fully wave-independent: znorm in registers + __shfl broadcast;
//    per-wave sIdx scratch (wave-local LDS, lgkmcnt-ordered, no barrier);
//    single block loss-reduce barrier at the end.
// Numerics identical to R14 (proven): negated-A + en/2 accumulator init
// (q = d/2, margin/2), packed top-2 via med3+min, bit-exact np re-eval /
// znorm / lexicographic tie-break. Loss atomicAdd into out[8388608].
// ---------------------------------------------------------------------------
template <int MODE>
__global__ __launch_bounds__(512, 4) void vq_main(
    const float* __restrict__ z, const float* __restrict__ E,
    const float* __restrict__ Et, const unsigned short* __restrict__ Eb,
    const float* __restrict__ enorm, float* __restrict__ out) {
    __shared__ unsigned short sB[32768];  // 64 KB: half codebook, 32 tiles
    __shared__ float sEn[1024];           // enorm * 0.5
    __shared__ int sIdxW[8][32];          // per-wave row winners
    __shared__ float sRed[8];

    const int tid = threadIdx.x;
    const int w = tid >> 6;
    const int l = tid & 63;
    const int quad = l >> 4;
    const int m = l & 15;
    const int b = blockIdx.x;
    const int R0 = (b * 8 + w) * 32;      // wave's first row (32 rows/wave)

    // stage half H (64 KB): wave w DMAs its 8 KB slice, 8 x 1KB dwordx4
    auto stageH = [&](int H) {
        const unsigned short* gp = Eb + H * 32768 + w * 4096 + l * 8;
        unsigned short* lp = &sB[w * 4096];
        #pragma unroll
        for (int i = 0; i < 8; ++i) {
            __builtin_amdgcn_global_load_lds(
                (const __attribute__((address_space(1))) void*)(gp + i * 512),
                (__attribute__((address_space(3))) void*)(lp + i * 512),
                16, 0, 0);
        }
    };

    // conversion fallback (MODE 2): build half H of the fragment layout in
    // LDS from strided E (identical f2b values / element mapping as prep)
    auto convertH = [&](int H) {
        unsigned* sW = (unsigned*)&sB[0];
        #pragma unroll
        for (int it = 0; it < 32; ++it) {
            const int W = it * 512 + tid;     // u32 word 0..16383
            const int cl = W >> 9;
            const int s2 = (W >> 8) & 1;
            const int ll = (W >> 2) & 63;
            const int j = (W & 3) * 2;
            const int d = s2 * 32 + (ll >> 4) * 8 + j;
            const int col = (H * 32 + cl) * 16 + (ll & 15);
            const unsigned lo = f2b(E[d * 1024 + col]);
            const unsigned hi = f2b(E[(d + 1) * 1024 + col]);
            sW[W] = lo | (hi << 16);
        }
    };

    if constexpr (MODE < 2) {
        stageH(0);                                    // DMA overlaps z-phase
        float2 e2 = ((const float2*)enorm)[tid];
        e2.x *= 0.5f; e2.y *= 0.5f;
        ((float2*)sEn)[tid] = e2;                     // sEn = enorm/2 (exact)
    } else {
        #pragma unroll
        for (int i = 0; i < 2; ++i) {
            const int col = tid + i * 512;
            float s2 = 0.f;
            #pragma unroll
            for (int d = 0; d < 64; ++d) {
                float v = E[d * 1024 + col];
                s2 = fmaf(v, v, s2);
            }
            sEn[col] = s2 * 0.5f;
        }
        convertH(0);
    }

    // A fragments for BOTH strips: bf16 RNE of -z (sign flip, exact)
    short8 a0[2], a1[2];
    #pragma unroll
    for (int s = 0; s < 2; ++s) {
        #pragma unroll
        for (int s2 = 0; s2 < 2; ++s2) {
            const float* zp = z + (R0 + s * 16 + m) * 64 + s2 * 32 + quad * 8;
            union { float4 v; float f[4]; } u0, u1;
            u0.v = *(const float4*)zp;
            u1.v = *(const float4*)(zp + 4);
            short8 av;
            #pragma unroll
            for (int j = 0; j < 4; ++j) av[j] = (short)(f2b(u0.f[j]) ^ 0x8000u);
            #pragma unroll
            for (int j = 0; j < 4; ++j) av[4 + j] = (short)(f2b(u1.f[j]) ^ 0x8000u);
            if (s == 0) a0[s2] = av; else a1[s2] = av;
        }
    }

    // znorm for both strips (lanes 0..15, strip rows R0+s*16+l):
    // bit-exact numpy pairwise sum (SSE path, 4 accumulators, hadd)
    float zn0 = 0.f, zn1 = 0.f;
    #pragma unroll
    for (int s = 0; s < 2; ++s) {
        if (l < 16) {
            const float* zr = z + (R0 + s * 16 + l) * 64;
            float S[16];
            #pragma unroll
            for (int u = 0; u < 16; ++u) { float v = zr[u]; S[u] = v * v; }
            #pragma unroll
            for (int t = 1; t < 4; ++t)
                #pragma unroll
                for (int u = 0; u < 16; ++u) {
                    float v = zr[16 * t + u];
                    float sq = v * v;
                    S[u] = S[u] + sq;
                }
            float Ra = (S[0] + S[4]) + (S[8] + S[12]);
            float Rb = (S[1] + S[5]) + (S[9] + S[13]);
            float Rc = (S[2] + S[6]) + (S[10] + S[14]);
            float Rd = (S[3] + S[7]) + (S[11] + S[15]);
            float zn = (Ra + Rb) + (Rc + Rd);
            if (s == 0) zn0 = zn; else zn1 = zn;
        }
    }

    // packed top-2 per lane per strip: q-value with tile idx in low 6 bits
    float v1p[2][4], v2p[2][4];
    #pragma unroll
    for (int s = 0; s < 2; ++s)
        #pragma unroll
        for (int r = 0; r < 4; ++r) { v1p[s][r] = 3.4e38f; v2p[s][r] = 3.4e38f; }

    // ---- two halves: stage/convert -> barrier -> barrier-free screen ----
    #pragma unroll
    for (int H = 0; H < 2; ++H) {
        if (H == 1) {
            __syncthreads();           // all waves done READING sB half 0
            if constexpr (MODE < 2) stageH(1); else convertH(1);
        }
        // drain staging DMA (and all LDS writes) then block-wide barrier
        asm volatile("s_waitcnt vmcnt(0) lgkmcnt(0)" ::: "memory");
        __builtin_amdgcn_sched_barrier(0);
        __builtin_amdgcn_s_barrier();

        // barrier-free screening: 32 tiles, ds_reads shared by both strips
        #pragma unroll 4
        for (int c = 0; c < 32; ++c) {
            const int gc = H * 32 + c;
            short8 b0 = *(const short8*)&sB[c * 1024 + l * 8];
            short8 b1 = *(const short8*)&sB[c * 1024 + 512 + l * 8];
            const float enh = sEn[gc * 16 + m];
            f32x4 acc0 = {enh, enh, enh, enh};     // q = en/2 - dot
            f32x4 acc1 = {enh, enh, enh, enh};
            acc0 = __builtin_amdgcn_mfma_f32_16x16x32_bf16(a0[0], b0, acc0, 0, 0, 0);
            acc0 = __builtin_amdgcn_mfma_f32_16x16x32_bf16(a0[1], b1, acc0, 0, 0, 0);
            acc1 = __builtin_amdgcn_mfma_f32_16x16x32_bf16(a1[0], b0, acc1, 0, 0, 0);
            acc1 = __builtin_amdgcn_mfma_f32_16x16x32_bf16(a1[1], b1, acc1, 0, 0, 0);
            #pragma unroll
            for (int r = 0; r < 4; ++r) {
                float p0 = __uint_as_float(
                    (__float_as_uint(acc0[r]) & 0xFFFFFFC0u) | (unsigned)gc);
                v2p[0][r] = __builtin_amdgcn_fmed3f(p0, v1p[0][r], v2p[0][r]);
                v1p[0][r] = fminf(p0, v1p[0][r]);
                float p1 = __uint_as_float(
                    (__float_as_uint(acc1[r]) & 0xFFFFFFC0u) | (unsigned)gc);
                v2p[1][r] = __builtin_amdgcn_fmed3f(p1, v1p[1][r], v2p[1][r]);
                v1p[1][r] = fminf(p1, v1p[1][r]);
            }
        }
    }

    // ---- tail: fully wave-independent (no block barriers until loss) ----
    constexpr bool viaEt = (MODE == 0);
    const float margin_q = MARGIN * 0.5f;   // q-space margin (q = d/2)
    float la = 0.f;
    #pragma unroll
    for (int s = 0; s < 2; ++s) {
        #pragma unroll
        for (int r = 0; r < 4; ++r) {
            float pv1 = v1p[s][r];
            float vb = pv1;
            #pragma unroll
            for (int mask = 1; mask <= 8; mask <<= 1)
                vb = fminf(vb, __shfl_xor(vb, mask));
            const int rowls = quad * 4 + r;          // strip-local row
            const float zn = __shfl(s == 0 ? zn0 : zn1, rowls);
            const float* zr = z + (R0 + s * 16 + rowls) * 64;
            float d = 3.4e38f;
            int kk = 0x7fffffff;
            if (pv1 <= vb + margin_q) {
                kk = (int)(__float_as_uint(pv1) & 63u) * 16 + m;
                d = viaEt ? np_dist<1>(zr, Et + kk * 64, zn, 2.f * sEn[kk])
                          : np_dist<1024>(zr, E + kk, zn, 2.f * sEn[kk]);
            }
            float pv2 = v2p[s][r];
            if (pv2 <= vb + margin_q) {
                int kc = (int)(__float_as_uint(pv2) & 63u) * 16 + m;
                float dd = viaEt ? np_dist<1>(zr, Et + kc * 64, zn, 2.f * sEn[kc])
                                 : np_dist<1024>(zr, E + kc, zn, 2.f * sEn[kc]);
                if (dd < d || (dd == d && kc < kk)) { d = dd; kk = kc; }
            }
            #pragma unroll
            for (int mask = 1; mask <= 8; mask <<= 1) {
                float d2 = __shfl_xor(d, mask);
                int c2 = __shfl_xor(kk, mask);
                bool take = (d2 < d) || (d2 == d && c2 < kk);
                d = take ? d2 : d;
                kk = take ? c2 : kk;
            }
            if (m == 0) {
                sIdxW[w][s * 16 + rowls] = kk;
                la += d;
            }
        }
    }

    // wave-local LDS ordering: our sIdx writes must land before our reads
    asm volatile("s_waitcnt lgkmcnt(0)" ::: "memory");

    // gather: 4 lanes/row, 16 dims each (contiguous from Et when available)
    #pragma unroll
    for (int s = 0; s < 2; ++s) {
        const int row_in = l >> 2;
        const int part = l & 3;
        const int idx = sIdxW[w][s * 16 + row_in];
        union { float ss[16]; float4 f[4]; } tmp;
        if (viaEt) {
            const float4* src = (const float4*)(Et + idx * 64 + part * 16);
            #pragma unroll
            for (int q4 = 0; q4 < 4; ++q4) tmp.f[q4] = src[q4];
        } else {
            #pragma unroll
            for (int dd = 0; dd < 16; ++dd)
                tmp.ss[dd] = E[(part * 16 + dd) * 1024 + idx];
        }
        float4* dst = (float4*)(out + (R0 + s * 16 + row_in) * 64 + part * 16);
        #pragma unroll
        for (int q4 = 0; q4 < 4; ++q4) dst[q4] = tmp.f[q4];
    }

    // loss: wave butterfly -> per-block reduce -> one atomic per block
    #pragma unroll
    for (int mask = 32; mask >= 1; mask >>= 1) la += __shfl_xor(la, mask);
    if (l == 0) sRed[w] = la;
    __syncthreads();
    if (tid == 0) {
        float bs = 0.f;
        #pragma unroll
        for (int i = 0; i < 8; ++i) bs += sRed[i];
        atomicAdd(out + 8388608, bs * (1.25f / 8388608.f));
    }
}

extern "C" void kernel_launch(void* const* d_in, const int* in_sizes, int n_in,
                              void* d_out, int out_size, void* d_ws, size_t ws_size,
                              hipStream_t stream) {
    const float* z = (const float*)d_in[0];  // fp32 [131072,64]
    const float* E = (const float*)d_in[1];  // fp32 [64,1024]
    float* out = (float*)d_out;              // fp32 [8388609]

    char* ws = (char*)d_ws;
    float* enorm = (float*)(ws + 128);                 // 4 KB
    unsigned short* Eb = (unsigned short*)(ws + 8192); // 128 KB fragment-layout bf16
    float* Et = (float*)(ws + 139264);                 // 256 KB fp32 transpose

    if (ws_size >= (size_t)401408) {
        vq_prep<true><<<16, 256, 0, stream>>>(E, enorm, Et, (unsigned*)Eb);
        vq_main<0><<<512, 512, 0, stream>>>(z, E, Et, Eb, enorm, out);
    } else if (ws_size >= (size_t)139264) {
        vq_prep<false><<<16, 256, 0, stream>>>(E, enorm, Et, (unsigned*)Eb);
        vq_main<1><<<512, 512, 0, stream>>>(z, E, Et, Eb, enorm, out);
    } else {
        vq_main<2><<<512, 512, 0, stream>>>(z, E, Et, Eb, enorm, out);
    }
}

// Round 17
// 142.255 us; speedup vs baseline: 6.7632x; 1.0056x over previous
//
#include <hip/hip_runtime.h>

#pragma clang fp contract(off)

typedef __attribute__((ext_vector_type(8))) short short8;
typedef __attribute__((ext_vector_type(4))) float f32x4;

#define MARGIN 0.02f

static __device__ __forceinline__ unsigned short f2b(float f) {
    union { float f; unsigned u; } x; x.f = f;
    unsigned u = x.u;
    return (unsigned short)((u + 0x7FFFu + ((u >> 16) & 1u)) >> 16);
}

// Bit-exact np distance, scalar-load form (strided codebook, ES elements).
template <int ES>
static __device__ __forceinline__ float np_dist(
    const float* __restrict__ zr, const float* __restrict__ ecol,
    float zn, float en) {
    float c = 0.f;
    #pragma unroll
    for (int i = 0; i < 64; ++i) c = fmaf(zr[i], ecol[i * ES], c);
    float t = zn - 2.f * c;
    return t + en;
}

// Bit-exact np distance, VECTOR-LOAD form (contiguous Et row, 256-B aligned).
// Loads via dwordx4 (4x fewer VMEM instructions/beats than 64 scalar dwords);
// the fmaf chain consumes elements in the IDENTICAL ascending single-
// accumulator order -> bit-identical result to the scalar form.
static __device__ __forceinline__ float np_dist_v(
    const float* __restrict__ zr, const float* __restrict__ ecol,
    float zn, float en) {
    const float4* zv4 = (const float4*)zr;
    const float4* ev4 = (const float4*)ecol;
    float c = 0.f;
    #pragma unroll
    for (int q = 0; q < 16; ++q) {
        float4 zv = zv4[q];
        float4 ev = ev4[q];
        c = fmaf(zv.x, ev.x, c);
        c = fmaf(zv.y, ev.y, c);
        c = fmaf(zv.z, ev.z, c);
        c = fmaf(zv.w, ev.w, c);
    }
    float t = zn - 2.f * c;
    return t + en;
}

// ---------------------------------------------------------------------------
// Prep kernel (grid 16 x 256) — SEPARATE LAUNCH. R6..R15-proven, unchanged.
// ---------------------------------------------------------------------------
template <bool ET>
__global__ __launch_bounds__(256) void vq_prep(
    const float* __restrict__ E, float* __restrict__ enorm,
    float* __restrict__ Et, unsigned* __restrict__ EbW) {
    __shared__ float sT[64][65];
    const int tid = threadIdx.x;
    const int w = tid >> 6;
    const int m64 = tid & 63;
    const int c0 = blockIdx.x * 64;

    #pragma unroll
    for (int r = 0; r < 16; ++r) {
        const int row = r * 4 + w;
        sT[row][m64] = E[row * 1024 + c0 + m64];
    }
    __syncthreads();

    if (ET) {
        #pragma unroll
        for (int it = 0; it < 16; ++it) {
            const int e = it * 256 + tid;   // 0..4095
            const int col = e >> 6, d = e & 63;
            Et[(c0 + col) * 64 + d] = sT[d][col];
        }
    }
    #pragma unroll
    for (int it = 0; it < 8; ++it) {
        const int w0 = it * 256 + tid;      // 0..2047 (u32 words)
        const int cl = w0 >> 9;
        const int s = (w0 >> 8) & 1;
        const int ll = (w0 >> 2) & 63;
        const int j = (w0 & 3) * 2;
        const int d = s * 32 + (ll >> 4) * 8 + j;
        const int col = cl * 16 + (ll & 15);
        const unsigned lo = f2b(sT[d][col]);
        const unsigned hi = f2b(sT[d + 1][col]);
        EbW[(blockIdx.x * 4 + cl) * 512 + (w0 & 511)] = lo | (hi << 16);
    }
    if (tid < 64) {
        float s2 = 0.f;
        #pragma unroll
        for (int d = 0; d < 64; ++d) {
            float v = sT[d][tid];
            s2 = fmaf(v, v, s2);
        }
        enorm[c0 + tid] = s2;
    }
}

// ---------------------------------------------------------------------------
// Main kernel. MODE 0: Et+Eb, 1: Eb only, 2: self-contained.
//
// R17 = R16 re-run (infra flake per R8->R9 precedent; audited delta vs the
// cleanly-passing R15 is branchless float4 loads only — no hang mechanism).
// R15 structure: 8 waves/block, half-codebook staged once, 4 barriers
// total, wave-independent tail. Tail vectorized: np_dist_v and znorm load
// via float4/dwordx4 (4x fewer VMEM instructions and line-beats on the
// scattered Et candidate rows) with bit-identical fmaf ordering.
// Numerics: negated-A + en/2 accumulator init (q = d/2, margin/2), packed
// top-2 via med3+min, bit-exact np re-eval / znorm / lexicographic
// tie-break. Loss atomicAdd into out[8388608] (harness zeroes out).
// ---------------------------------------------------------------------------
template <int MODE>
__global__ __launch_bounds__(512, 4) void vq_main(
    const float* __restrict__ z, const float* __restrict__ E,
    const float* __restrict__ Et, const unsigned short* __restrict__ Eb,
    const float* __restrict__ enorm, float* __restrict__ out) {
    __shared__ unsigned short sB[32768];  // 64 KB: half codebook, 32 tiles
    __shared__ float sEn[1024];           // enorm * 0.5
    __shared__ int sIdxW[8][32];          // per-wave row winners
    __shared__ float sRed[8];

    const int tid = threadIdx.x;
    const int w = tid >> 6;
    const int l = tid & 63;
    const int quad = l >> 4;
    const int m = l & 15;
    const int b = blockIdx.x;
    const int R0 = (b * 8 + w) * 32;      // wave's first row (32 rows/wave)

    // stage half H (64 KB): wave w DMAs its 8 KB slice, 8 x 1KB dwordx4
    auto stageH = [&](int H) {
        const unsigned short* gp = Eb + H * 32768 + w * 4096 + l * 8;
        unsigned short* lp = &sB[w * 4096];
        #pragma unroll
        for (int i = 0; i < 8; ++i) {
            __builtin_amdgcn_global_load_lds(
                (const __attribute__((address_space(1))) void*)(gp + i * 512),
                (__attribute__((address_space(3))) void*)(lp + i * 512),
                16, 0, 0);
        }
    };

    // conversion fallback (MODE 2): build half H of the fragment layout in
    // LDS from strided E (identical f2b values / element mapping as prep)
    auto convertH = [&](int H) {
        unsigned* sW = (unsigned*)&sB[0];
        #pragma unroll
        for (int it = 0; it < 32; ++it) {
            const int W = it * 512 + tid;     // u32 word 0..16383
            const int cl = W >> 9;
            const int s2 = (W >> 8) & 1;
            const int ll = (W >> 2) & 63;
            const int j = (W & 3) * 2;
            const int d = s2 * 32 + (ll >> 4) * 8 + j;
            const int col = (H * 32 + cl) * 16 + (ll & 15);
            const unsigned lo = f2b(E[d * 1024 + col]);
            const unsigned hi = f2b(E[(d + 1) * 1024 + col]);
            sW[W] = lo | (hi << 16);
        }
    };

    if constexpr (MODE < 2) {
        stageH(0);                                    // DMA overlaps z-phase
        float2 e2 = ((const float2*)enorm)[tid];
        e2.x *= 0.5f; e2.y *= 0.5f;
        ((float2*)sEn)[tid] = e2;                     // sEn = enorm/2 (exact)
    } else {
        #pragma unroll
        for (int i = 0; i < 2; ++i) {
            const int col = tid + i * 512;
            float s2 = 0.f;
            #pragma unroll
            for (int d = 0; d < 64; ++d) {
                float v = E[d * 1024 + col];
                s2 = fmaf(v, v, s2);
            }
            sEn[col] = s2 * 0.5f;
        }
        convertH(0);
    }

    // A fragments for BOTH strips: bf16 RNE of -z (sign flip, exact)
    short8 a0[2], a1[2];
    #pragma unroll
    for (int s = 0; s < 2; ++s) {
        #pragma unroll
        for (int s2 = 0; s2 < 2; ++s2) {
            const float* zp = z + (R0 + s * 16 + m) * 64 + s2 * 32 + quad * 8;
            union { float4 v; float f[4]; } u0, u1;
            u0.v = *(const float4*)zp;
            u1.v = *(const float4*)(zp + 4);
            short8 av;
            #pragma unroll
            for (int j = 0; j < 4; ++j) av[j] = (short)(f2b(u0.f[j]) ^ 0x8000u);
            #pragma unroll
            for (int j = 0; j < 4; ++j) av[4 + j] = (short)(f2b(u1.f[j]) ^ 0x8000u);
            if (s == 0) a0[s2] = av; else a1[s2] = av;
        }
    }

    // znorm for both strips (lanes 0..15, strip rows R0+s*16+l):
    // bit-exact numpy pairwise sum (SSE path, 4 accumulators, hadd);
    // float4 vector loads, element consumption order UNCHANGED.
    float zn0 = 0.f, zn1 = 0.f;
    #pragma unroll
    for (int s = 0; s < 2; ++s) {
        if (l < 16) {
            const float4* zr4 = (const float4*)(z + (R0 + s * 16 + l) * 64);
            float S[16];
            #pragma unroll
            for (int q = 0; q < 4; ++q) {
                float4 v = zr4[q];
                S[q * 4 + 0] = v.x * v.x;
                S[q * 4 + 1] = v.y * v.y;
                S[q * 4 + 2] = v.z * v.z;
                S[q * 4 + 3] = v.w * v.w;
            }
            #pragma unroll
            for (int t = 1; t < 4; ++t)
                #pragma unroll
                for (int q = 0; q < 4; ++q) {
                    float4 v = zr4[t * 4 + q];
                    float sqx = v.x * v.x; S[q * 4 + 0] = S[q * 4 + 0] + sqx;
                    float sqy = v.y * v.y; S[q * 4 + 1] = S[q * 4 + 1] + sqy;
                    float sqz = v.z * v.z; S[q * 4 + 2] = S[q * 4 + 2] + sqz;
                    float sqw = v.w * v.w; S[q * 4 + 3] = S[q * 4 + 3] + sqw;
                }
            float Ra = (S[0] + S[4]) + (S[8] + S[12]);
            float Rb = (S[1] + S[5]) + (S[9] + S[13]);
            float Rc = (S[2] + S[6]) + (S[10] + S[14]);
            float Rd = (S[3] + S[7]) + (S[11] + S[15]);
            float zn = (Ra + Rb) + (Rc + Rd);
            if (s == 0) zn0 = zn; else zn1 = zn;
        }
    }

    // packed top-2 per lane per strip: q-value with tile idx in low 6 bits
    float v1p[2][4], v2p[2][4];
    #pragma unroll
    for (int s = 0; s < 2; ++s)
        #pragma unroll
        for (int r = 0; r < 4; ++r) { v1p[s][r] = 3.4e38f; v2p[s][r] = 3.4e38f; }

    // ---- two halves: stage/convert -> barrier -> barrier-free screen ----
    #pragma unroll
    for (int H = 0; H < 2; ++H) {
        if (H == 1) {
            __syncthreads();           // all waves done READING sB half 0
            if constexpr (MODE < 2) stageH(1); else convertH(1);
        }
        // drain staging DMA (and all LDS writes) then block-wide barrier
        asm volatile("s_waitcnt vmcnt(0) lgkmcnt(0)" ::: "memory");
        __builtin_amdgcn_sched_barrier(0);
        __builtin_amdgcn_s_barrier();

        // barrier-free screening: 32 tiles, ds_reads shared by both strips
        #pragma unroll 4
        for (int c = 0; c < 32; ++c) {
            const int gc = H * 32 + c;
            short8 b0 = *(const short8*)&sB[c * 1024 + l * 8];
            short8 b1 = *(const short8*)&sB[c * 1024 + 512 + l * 8];
            const float enh = sEn[gc * 16 + m];
            f32x4 acc0 = {enh, enh, enh, enh};     // q = en/2 - dot
            f32x4 acc1 = {enh, enh, enh, enh};
            acc0 = __builtin_amdgcn_mfma_f32_16x16x32_bf16(a0[0], b0, acc0, 0, 0, 0);
            acc0 = __builtin_amdgcn_mfma_f32_16x16x32_bf16(a0[1], b1, acc0, 0, 0, 0);
            acc1 = __builtin_amdgcn_mfma_f32_16x16x32_bf16(a1[0], b0, acc1, 0, 0, 0);
            acc1 = __builtin_amdgcn_mfma_f32_16x16x32_bf16(a1[1], b1, acc1, 0, 0, 0);
            #pragma unroll
            for (int r = 0; r < 4; ++r) {
                float p0 = __uint_as_float(
                    (__float_as_uint(acc0[r]) & 0xFFFFFFC0u) | (unsigned)gc);
                v2p[0][r] = __builtin_amdgcn_fmed3f(p0, v1p[0][r], v2p[0][r]);
                v1p[0][r] = fminf(p0, v1p[0][r]);
                float p1 = __uint_as_float(
                    (__float_as_uint(acc1[r]) & 0xFFFFFFC0u) | (unsigned)gc);
                v2p[1][r] = __builtin_amdgcn_fmed3f(p1, v1p[1][r], v2p[1][r]);
                v1p[1][r] = fminf(p1, v1p[1][r]);
            }
        }
    }

    // ---- tail: fully wave-independent (no block barriers until loss) ----
    constexpr bool viaEt = (MODE == 0);
    const float margin_q = MARGIN * 0.5f;   // q-space margin (q = d/2)
    float la = 0.f;
    #pragma unroll
    for (int s = 0; s < 2; ++s) {
        #pragma unroll
        for (int r = 0; r < 4; ++r) {
            float pv1 = v1p[s][r];
            float vb = pv1;
            #pragma unroll
            for (int mask = 1; mask <= 8; mask <<= 1)
                vb = fminf(vb, __shfl_xor(vb, mask));
            const int rowls = quad * 4 + r;          // strip-local row
            const float zn = __shfl(s == 0 ? zn0 : zn1, rowls);
            const float* zr = z + (R0 + s * 16 + rowls) * 64;
            float d = 3.4e38f;
            int kk = 0x7fffffff;
            if (pv1 <= vb + margin_q) {
                kk = (int)(__float_as_uint(pv1) & 63u) * 16 + m;
                d = viaEt ? np_dist_v(zr, Et + kk * 64, zn, 2.f * sEn[kk])
                          : np_dist<1024>(zr, E + kk, zn, 2.f * sEn[kk]);
            }
            float pv2 = v2p[s][r];
            if (pv2 <= vb + margin_q) {
                int kc = (int)(__float_as_uint(pv2) & 63u) * 16 + m;
                float dd = viaEt ? np_dist_v(zr, Et + kc * 64, zn, 2.f * sEn[kc])
                                 : np_dist<1024>(zr, E + kc, zn, 2.f * sEn[kc]);
                if (dd < d || (dd == d && kc < kk)) { d = dd; kk = kc; }
            }
            #pragma unroll
            for (int mask = 1; mask <= 8; mask <<= 1) {
                float d2 = __shfl_xor(d, mask);
                int c2 = __shfl_xor(kk, mask);
                bool take = (d2 < d) || (d2 == d && c2 < kk);
                d = take ? d2 : d;
                kk = take ? c2 : kk;
            }
            if (m == 0) {
                sIdxW[w][s * 16 + rowls] = kk;
                la += d;
            }
        }
    }

    // wave-local LDS ordering: our sIdx writes must land before our reads
    asm volatile("s_waitcnt lgkmcnt(0)" ::: "memory");

    // gather: 4 lanes/row, 16 dims each (contiguous from Et when available)
    #pragma unroll
    for (int s = 0; s < 2; ++s) {
        const int row_in = l >> 2;
        const int part = l & 3;
        const int idx = sIdxW[w][s * 16 + row_in];
        union { float ss[16]; float4 f[4]; } tmp;
        if (viaEt) {
            const float4* src = (const float4*)(Et + idx * 64 + part * 16);
            #pragma unroll
            for (int q4 = 0; q4 < 4; ++q4) tmp.f[q4] = src[q4];
        } else {
            #pragma unroll
            for (int dd = 0; dd < 16; ++dd)
                tmp.ss[dd] = E[(part * 16 + dd) * 1024 + idx];
        }
        float4* dst = (float4*)(out + (R0 + s * 16 + row_in) * 64 + part * 16);
        #pragma unroll
        for (int q4 = 0; q4 < 4; ++q4) dst[q4] = tmp.f[q4];
    }

    // loss: wave butterfly -> per-block reduce -> one atomic per block
    #pragma unroll
    for (int mask = 32; mask >= 1; mask >>= 1) la += __shfl_xor(la, mask);
    if (l == 0) sRed[w] = la;
    __syncthreads();
    if (tid == 0) {
        float bs = 0.f;
        #pragma unroll
        for (int i = 0; i < 8; ++i) bs += sRed[i];
        atomicAdd(out + 8388608, bs * (1.25f / 8388608.f));
    }
}

extern "C" void kernel_launch(void* const* d_in, const int* in_sizes, int n_in,
                              void* d_out, int out_size, void* d_ws, size_t ws_size,
                              hipStream_t stream) {
    const float* z = (const float*)d_in[0];  // fp32 [131072,64]
    const float* E = (const float*)d_in[1];  // fp32 [64,1024]
    float* out = (float*)d_out;              // fp32 [8388609]

    char* ws = (char*)d_ws;
    float* enorm = (float*)(ws + 128);                 // 4 KB
    unsigned short* Eb = (unsigned short*)(ws + 8192); // 128 KB fragment-layout bf16
    float* Et = (float*)(ws + 139264);                 // 256 KB fp32 transpose

    if (ws_size >= (size_t)401408) {
        vq_prep<true><<<16, 256, 0, stream>>>(E, enorm, Et, (unsigned*)Eb);
        vq_main<0><<<512, 512, 0, stream>>>(z, E, Et, Eb, enorm, out);
    } else if (ws_size >= (size_t)139264) {
        vq_prep<false><<<16, 256, 0, stream>>>(E, enorm, Et, (unsigned*)Eb);
        vq_main<1><<<512, 512, 0, stream>>>(z, E, Et, Eb, enorm, out);
    } else {
        vq_main<2><<<512, 512, 0, stream>>>(z, E, Et, Eb, enorm, out);
    }
}